// Round 1
// baseline (409.415 us; speedup 1.0000x reference)
//
#include <hip/hip_runtime.h>

#define A_ANCH 102400
#define BATCH  16
#define N_ANN  32
#define NLDM   196
#define ANNW   200   // 4 box + 196 landmark floats per annotation row

// ws layout:
//   [0,    384)  : double acc[B][3]  (pos_sum, bbox_sum, ldm_sum)
//   [1024, 1280) : int    cnts[B][4] (npos, nneg, nl, unused)
//   [4096, ...)  : unsigned keys[B][A]  (sortable desc keys of neg losses; 0 for non-neg)

__global__ __launch_bounds__(64) void k_zero(double* acc, int* cnts) {
    int t = threadIdx.x;
    if (t < BATCH * 3) acc[t] = 0.0;
    if (t < BATCH * 4) cnts[t] = 0;
}

__global__ __launch_bounds__(256) void k_main(
    const float* __restrict__ cls,      // B*A*2
    const float* __restrict__ breg,     // B*A*4
    const float* __restrict__ lreg,     // B*A*196
    const float* __restrict__ anchors,  // A*4
    const float* __restrict__ ann,      // B*32*200
    double* __restrict__ acc,
    int* __restrict__ cnts,
    unsigned* __restrict__ keys)
{
    const int tid = threadIdx.x;
    const int blocksPer = A_ANCH / 256; // 400
    const int b = blockIdx.x / blocksPer;
    const int a = (blockIdx.x % blocksPer) * 256 + tid;

    __shared__ float4 sbox[N_ANN];
    __shared__ int    svalid[N_ANN];
    if (tid < N_ANN) {
        float4 bx = *reinterpret_cast<const float4*>(ann + (size_t)(b * N_ANN + tid) * ANNW);
        sbox[tid] = bx;
        svalid[tid] = bx.x > 0.0f;
    }
    __syncthreads();

    float4 av = *reinterpret_cast<const float4*>(anchors + (size_t)a * 4);
    const float aw = av.z - av.x, ah = av.w - av.y;
    const float areaA = aw * ah;

    float best = -1e30f; int arg = 0;
    #pragma unroll
    for (int j = 0; j < N_ANN; ++j) {
        float4 bx = sbox[j];
        float areaB = (bx.z - bx.x) * (bx.w - bx.y);
        float iw = fminf(av.z, bx.z) - fmaxf(av.x, bx.x);
        float ih = fminf(av.w, bx.w) - fmaxf(av.y, bx.y);
        iw = fmaxf(iw, 0.0f); ih = fmaxf(ih, 0.0f);
        float inter = iw * ih;
        float ua = fmaxf(areaA + areaB - inter, 1e-8f);
        float v = svalid[j] ? (inter / ua) : -1.0f;
        if (v > best) { best = v; arg = j; }
    }
    const bool pos = best >= 0.7f;
    const bool neg = best < 0.4f;

    float2 c = *reinterpret_cast<const float2*>(cls + ((size_t)b * A_ANCH + a) * 2);

    // sortable key for descending float order: larger value -> larger key
    float nv = -c.y;
    unsigned bits = __float_as_uint(nv);
    unsigned key = (bits & 0x80000000u) ? ~bits : (bits ^ 0x80000000u);
    keys[(size_t)b * A_ANCH + a] = neg ? key : 0u;

    unsigned long long bp = __ballot(pos);
    unsigned long long bn = __ballot(neg);
    if ((tid & 63) == 0) {
        if (bp) atomicAdd(&cnts[b * 4 + 0], (int)__popcll(bp));
        if (bn) atomicAdd(&cnts[b * 4 + 1], (int)__popcll(bn));
    }

    if (pos) {
        atomicAdd(&acc[b * 3 + 0], (double)(-c.x));

        const float acx = av.x + 0.5f * aw, acy = av.y + 0.5f * ah;
        float4 gb = sbox[arg];
        float gw = gb.z - gb.x, gh = gb.w - gb.y;
        float gcx = gb.x + 0.5f * gw, gcy = gb.y + 0.5f * gh;
        float tdx = (gcx - acx) / (aw + 1e-14f);
        float tdy = (gcy - acy) / (ah + 1e-14f);
        float tdw = logf(gw / aw);
        float tdh = logf(gh / ah);
        float t0 = tdx / 0.1f, t1 = tdy / 0.1f, t2 = tdw / 0.2f, t3 = tdh / 0.2f;

        float4 rv = *reinterpret_cast<const float4*>(breg + ((size_t)b * A_ANCH + a) * 4);
        float bsum = 0.0f, d;
        d = fabsf(t0 - rv.x); bsum += (d < 1.0f) ? 0.5f * d * d : d - 0.5f;
        d = fabsf(t1 - rv.y); bsum += (d < 1.0f) ? 0.5f * d * d : d - 0.5f;
        d = fabsf(t2 - rv.z); bsum += (d < 1.0f) ? 0.5f * d * d : d - 0.5f;
        d = fabsf(t3 - rv.w); bsum += (d < 1.0f) ? 0.5f * d * d : d - 0.5f;
        atomicAdd(&acc[b * 3 + 1], (double)bsum);

        // landmarks: only if matched GT has nonzero landmark sum
        const float* gl = ann + (size_t)(b * N_ANN + arg) * ANNW + 4;
        float glsum = 0.0f;
        for (int i = 0; i < NLDM; ++i) glsum += gl[i];
        if (glsum > 0.0f) {
            atomicAdd(&cnts[b * 4 + 2], 1);
            const float* lr = lreg + ((size_t)b * A_ANCH + a) * NLDM;
            double wsum = 0.0;
            for (int i = 0; i < NLDM; ++i) {
                float ctr = ((i & 1) == 0) ? acx : acy;
                float den = (((i & 1) == 0) ? aw : ah) + 1e-14f;
                float ltgt = (gl[i] - ctr) / den / 0.1f;
                float s = (i < 68) ? 1.0f : 3.0f;
                float ta = ltgt * s, tb = lr[i] * s;
                float dd = fabsf(ta - tb);
                float wing = (dd < 3.0f) ? 3.0f * log1pf(dd * 0.5f)
                                         : dd - 0.25112780437753474f; // WING_C
                wsum += (double)wing;
            }
            atomicAdd(&acc[b * 3 + 2], wsum);
        }
    }
}

__global__ __launch_bounds__(1024) void k_select(
    const float* __restrict__ ann,
    const double* __restrict__ acc,
    const int* __restrict__ cnts,
    const unsigned* __restrict__ keys,
    float* __restrict__ out)
{
    const int b = blockIdx.x;
    const int tid = threadIdx.x;
    const int NT = 1024;

    __shared__ unsigned hist[256];
    __shared__ unsigned s_prefix;
    __shared__ int s_remaining;
    __shared__ int s_hasgt;
    __shared__ double sred[16];

    if (tid == 0) {
        int hg = 0;
        for (int j = 0; j < N_ANN; ++j) hg |= (ann[(size_t)(b * N_ANN + j) * ANNW] > 0.0f) ? 1 : 0;
        s_hasgt = hg;
    }
    __syncthreads();

    const int npos = cnts[b * 4 + 0];
    const int nneg = cnts[b * 4 + 1];
    const int nl   = cnts[b * 4 + 2];
    const int hasgt = s_hasgt;
    const int keep = min(nneg, 3 * npos);

    const unsigned* k = keys + (size_t)b * A_ANCH;

    double total = 0.0;
    int remaining = 0;
    unsigned T = 0;

    if (hasgt && npos > 0 && keep > 0) {
        unsigned prefix = 0;
        remaining = keep;
        for (int pass = 0; pass < 4; ++pass) {
            const int shift = 24 - 8 * pass;
            for (int i = tid; i < 256; i += NT) hist[i] = 0;
            __syncthreads();
            const unsigned mask = pass ? (0xFFFFFFFFu << (shift + 8)) : 0u;
            for (int i = tid; i < A_ANCH; i += NT) {
                unsigned kk = k[i];
                if ((kk & mask) == prefix)
                    atomicAdd(&hist[(kk >> shift) & 0xFFu], 1u);
            }
            __syncthreads();
            if (tid == 0) {
                unsigned cum = 0;
                for (int bin = 255; bin >= 0; --bin) {
                    unsigned cc = hist[bin];
                    if (cum + cc >= (unsigned)remaining) {
                        s_remaining = remaining - (int)cum;
                        s_prefix = prefix | ((unsigned)bin << shift);
                        break;
                    }
                    cum += cc;
                }
            }
            __syncthreads();
            prefix = s_prefix; remaining = s_remaining;
            __syncthreads();
        }
        T = prefix;

        double lsum = 0.0;
        for (int i = tid; i < A_ANCH; i += NT) {
            unsigned kk = k[i];
            if (kk > T) {
                unsigned vb = (kk & 0x80000000u) ? (kk ^ 0x80000000u) : ~kk;
                lsum += (double)__uint_as_float(vb);
            }
        }
        #pragma unroll
        for (int off = 32; off > 0; off >>= 1) lsum += __shfl_down(lsum, off);
        if ((tid & 63) == 0) sred[tid >> 6] = lsum;
        __syncthreads();
        if (tid == 0) {
            double tt = 0.0;
            for (int w = 0; w < NT / 64; ++w) tt += sred[w];
            unsigned vb = (T & 0x80000000u) ? (T ^ 0x80000000u) : ~T;
            total = tt + (double)remaining * (double)__uint_as_float(vb);
        }
    }

    if (tid == 0) {
        double cls_l = 0.0, bbox_l = 0.0, ldm_l = 0.0;
        if (hasgt && npos > 0) {
            double neg_mean = (keep > 0) ? total / (double)keep : 0.0;
            cls_l = acc[b * 3 + 0] / (double)npos + neg_mean;
            bbox_l = acc[b * 3 + 1] / ((double)npos * 4.0);
        }
        if (hasgt && nl > 0) {
            ldm_l = acc[b * 3 + 2] / ((double)nl * 196.0);
        }
        out[b]          = (float)cls_l;
        out[BATCH + b]  = (float)bbox_l;
        out[2 * BATCH + b] = (float)ldm_l;
    }
}

extern "C" void kernel_launch(void* const* d_in, const int* in_sizes, int n_in,
                              void* d_out, int out_size, void* d_ws, size_t ws_size,
                              hipStream_t stream) {
    const float* cls     = (const float*)d_in[0];
    const float* breg    = (const float*)d_in[1];
    const float* lreg    = (const float*)d_in[2];
    const float* anchors = (const float*)d_in[3];
    const float* ann     = (const float*)d_in[4];

    double*   acc  = (double*)d_ws;
    int*      cnts = (int*)((char*)d_ws + 1024);
    unsigned* keys = (unsigned*)((char*)d_ws + 4096);
    float*    out  = (float*)d_out;

    hipLaunchKernelGGL(k_zero, dim3(1), dim3(64), 0, stream, acc, cnts);
    hipLaunchKernelGGL(k_main, dim3(BATCH * (A_ANCH / 256)), dim3(256), 0, stream,
                       cls, breg, lreg, anchors, ann, acc, cnts, keys);
    hipLaunchKernelGGL(k_select, dim3(BATCH), dim3(1024), 0, stream,
                       ann, acc, cnts, keys, out);
}